// Round 2
// baseline (1102.889 us; speedup 1.0000x reference)
//
#include <hip/hip_runtime.h>
#include <stddef.h>

typedef unsigned short ushort_t;
typedef __attribute__((ext_vector_type(8))) __bf16 bf16x8;
typedef __attribute__((ext_vector_type(4))) float f32x4;

#define BM 128
#define BN 128
#define BK 32
#define NDIM 4096
#define KDIM 4096
#define IN_OCT 512

// ---------------------------------------------------------------------------
// helpers
// ---------------------------------------------------------------------------
__device__ __forceinline__ void load_lds16(const void* g, void* l) {
    __builtin_amdgcn_global_load_lds(
        (const __attribute__((address_space(1))) void*)g,
        (__attribute__((address_space(3))) void*)l,
        16, 0, 0);
}

__device__ __host__ __forceinline__ ushort_t f2bf(float f) {
    union { float f; unsigned u; } c; c.f = f;
    unsigned u = c.u;
    return (ushort_t)((u + 0x7FFFu + ((u >> 16) & 1u)) >> 16);  // RNE
}

// ---------------------------------------------------------------------------
// x fp32 [M*K] -> bf16 [M*K].  8 floats / thread.
// ---------------------------------------------------------------------------
__global__ __launch_bounds__(256) void convert_x(const float* __restrict__ x,
                                                 ushort_t* __restrict__ xb) {
    const size_t t = (size_t)blockIdx.x * 256 + threadIdx.x;
    const float4* src = (const float4*)x;
    float4 v0 = src[2 * t];
    float4 v1 = src[2 * t + 1];
    union { uint4 v; ushort_t u[8]; } d;
    d.u[0] = f2bf(v0.x); d.u[1] = f2bf(v0.y); d.u[2] = f2bf(v0.z); d.u[3] = f2bf(v0.w);
    d.u[4] = f2bf(v1.x); d.u[5] = f2bf(v1.y); d.u[6] = f2bf(v1.z); d.u[7] = f2bf(v1.w);
    ((uint4*)xb)[t] = d.v;
}

// ---------------------------------------------------------------------------
// w_eff bf16 [4096 x 4096] from fp32 weight [512][512][8]:
//   w_eff[o*8+k][i*8+b] = s(k,b) * w[o][i][k^b]   (a(k,b) = k XOR b; Fano
//   lines are XOR-closed). Sign bit from smask bit (k*8+b). One thread per
//   (g, i): 32B fp32 read -> xor-shuffle -> 16B bf16 write. g is uniform per
//   block so the shuffle selects are scalar-predicated.
// ---------------------------------------------------------------------------
__global__ __launch_bounds__(256) void build_weff(const float* __restrict__ w,
                                                  ushort_t* __restrict__ weff,
                                                  unsigned long long smask) {
    const int t = blockIdx.x * 256 + threadIdx.x;   // [0, 4096*512)
    const int g = t >> 9;                           // row of w_eff (uniform/block)
    const int i = t & 511;
    const int o = g >> 3;
    const int k = g & 7;

    const float* wp = w + (((size_t)o * IN_OCT + i) << 3);
    float4 w0 = ((const float4*)wp)[0];
    float4 w1 = ((const float4*)wp)[1];
    float v[8] = {w0.x, w0.y, w0.z, w0.w, w1.x, w1.y, w1.z, w1.w};

    // t3[b] = v[b ^ k] via 3-stage xor shuffle (constant indices)
    float t1[8], t2[8], t3[8];
#pragma unroll
    for (int b = 0; b < 8; ++b) t1[b] = (k & 1) ? v[b ^ 1] : v[b];
#pragma unroll
    for (int b = 0; b < 8; ++b) t2[b] = (k & 2) ? t1[b ^ 2] : t1[b];
#pragma unroll
    for (int b = 0; b < 8; ++b) t3[b] = (k & 4) ? t2[b ^ 4] : t2[b];

    union { uint4 v; ushort_t u[8]; } d;
#pragma unroll
    for (int b = 0; b < 8; ++b) {
        ushort_t neg = (ushort_t)((smask >> (k * 8 + b)) & 1ull);
        d.u[b] = f2bf(t3[b]) ^ (ushort_t)(neg << 15);
    }
    ((uint4*)(weff + (size_t)g * KDIM))[i] = d.v;
}

// ---------------------------------------------------------------------------
// Path A GEMM: C[m][n] = sum_k A[m][k]*Bt[n][k] + bias[n]; A,Bt bf16; C fp32.
// m97 structure: 128x128 tile, BK=32, 4 waves, 4x4 mfma_16x16x32_bf16 each,
// global_load_lds width=16 staging, ds_read_b128 fragments.
// ---------------------------------------------------------------------------
__global__ __launch_bounds__(256) void oct_gemm(const ushort_t* __restrict__ A,
                                                const ushort_t* __restrict__ Bt,
                                                const float* __restrict__ bias,
                                                float* __restrict__ C) {
    __shared__ __align__(16) ushort_t sA[BM * BK];   // 8 KiB
    __shared__ __align__(16) ushort_t sB[BN * BK];   // 8 KiB

    const int tid  = threadIdx.x;
    const int lane = tid & 63;
    const int wave = tid >> 6;
    const int m0 = blockIdx.y * BM;
    const int n0 = blockIdx.x * BN;
    const int wm = (wave >> 1) * 64;
    const int wn = (wave & 1) * 64;
    const int lr   = lane & 15;
    const int quad = lane >> 4;

    const int srow = tid >> 2;          // staging row (covers 64 rows/issue)
    const int scol = (tid & 3) * 8;     // staging col

    f32x4 acc[4][4];
#pragma unroll
    for (int im = 0; im < 4; ++im)
#pragma unroll
        for (int in = 0; in < 4; ++in)
            acc[im][in] = (f32x4){0.f, 0.f, 0.f, 0.f};

    char* lbaseA = (char*)sA + wave * 1024;
    char* lbaseB = (char*)sB + wave * 1024;

    for (int k0 = 0; k0 < KDIM; k0 += BK) {
        __syncthreads();
        {
            const ushort_t* gA0 = A  + (size_t)(m0 + srow)      * KDIM + k0 + scol;
            const ushort_t* gA1 = A  + (size_t)(m0 + 64 + srow) * KDIM + k0 + scol;
            const ushort_t* gB0 = Bt + (size_t)(n0 + srow)      * KDIM + k0 + scol;
            const ushort_t* gB1 = Bt + (size_t)(n0 + 64 + srow) * KDIM + k0 + scol;
            load_lds16(gA0, lbaseA);
            load_lds16(gA1, lbaseA + 4096);
            load_lds16(gB0, lbaseB);
            load_lds16(gB1, lbaseB + 4096);
        }
        __syncthreads();

        bf16x8 af[4], bf[4];
#pragma unroll
        for (int im = 0; im < 4; ++im)
            af[im] = *(const bf16x8*)&sA[(wm + im * 16 + lr) * BK + quad * 8];
#pragma unroll
        for (int in = 0; in < 4; ++in)
            bf[in] = *(const bf16x8*)&sB[(wn + in * 16 + lr) * BK + quad * 8];

#pragma unroll
        for (int im = 0; im < 4; ++im)
#pragma unroll
            for (int in = 0; in < 4; ++in)
                acc[im][in] = __builtin_amdgcn_mfma_f32_16x16x32_bf16(
                    af[im], bf[in], acc[im][in], 0, 0, 0);
    }

    float bv[4];
#pragma unroll
    for (int in = 0; in < 4; ++in)
        bv[in] = bias[n0 + wn + in * 16 + lr];

#pragma unroll
    for (int im = 0; im < 4; ++im)
#pragma unroll
        for (int in = 0; in < 4; ++in) {
            const int gn = n0 + wn + in * 16 + lr;
#pragma unroll
            for (int r = 0; r < 4; ++r) {
                const int gm = m0 + wm + im * 16 + quad * 4 + r;
                C[(size_t)gm * NDIM + gn] = acc[im][in][r] + bv[in];
            }
        }
}

// ---------------------------------------------------------------------------
// Path B (fallback, zero workspace): same GEMM but stages fp32 -> bf16 in
// LDS via regular loads + ds_write, building w_eff tiles on the fly.
// ---------------------------------------------------------------------------
__global__ __launch_bounds__(256) void oct_gemm_fused(const float* __restrict__ A,
                                                      const float* __restrict__ W,
                                                      const float* __restrict__ bias,
                                                      float* __restrict__ C,
                                                      unsigned long long smask) {
    __shared__ __align__(16) ushort_t sA[BM * BK];
    __shared__ __align__(16) ushort_t sB[BN * BK];

    const int tid  = threadIdx.x;
    const int lane = tid & 63;
    const int wave = tid >> 6;
    const int m0 = blockIdx.y * BM;
    const int n0 = blockIdx.x * BN;
    const int wm = (wave >> 1) * 64;
    const int wn = (wave & 1) * 64;
    const int lr   = lane & 15;
    const int quad = lane >> 4;

    f32x4 acc[4][4];
#pragma unroll
    for (int im = 0; im < 4; ++im)
#pragma unroll
        for (int in = 0; in < 4; ++in)
            acc[im][in] = (f32x4){0.f, 0.f, 0.f, 0.f};

    for (int k0 = 0; k0 < KDIM; k0 += BK) {
        __syncthreads();
        // A tile: 128x32, 4 floats/thread/round, 4 rounds
#pragma unroll
        for (int r = 0; r < 4; ++r) {
            const int idx = r * 1024 + tid * 4;
            const int row = idx >> 5, col = idx & 31;
            float4 v = *(const float4*)(A + (size_t)(m0 + row) * KDIM + k0 + col);
            union { unsigned long long q; ushort_t u[4]; } d;
            d.u[0] = f2bf(v.x); d.u[1] = f2bf(v.y); d.u[2] = f2bf(v.z); d.u[3] = f2bf(v.w);
            *(unsigned long long*)&sA[row * BK + col] = d.q;
        }
        // B tile: rows g = n0+row of w_eff, built on the fly
#pragma unroll
        for (int r = 0; r < 4; ++r) {
            const int idx = r * 1024 + tid * 4;
            const int row = idx >> 5, col = idx & 31;
            const int g = n0 + row, o = g >> 3, k = g & 7;
            const int c = k0 + col;
            const int i = c >> 3, bb = c & 7;
            const float* base = W + (((size_t)o * IN_OCT + i) << 3);
            union { unsigned long long q; ushort_t u[4]; } d;
#pragma unroll
            for (int j = 0; j < 4; ++j) {
                const int b = bb + j;
                float v = base[k ^ b];
                ushort_t neg = (ushort_t)((smask >> (k * 8 + b)) & 1ull);
                d.u[j] = f2bf(v) ^ (ushort_t)(neg << 15);
            }
            *(unsigned long long*)&sB[row * BK + col] = d.q;
        }
        __syncthreads();

        bf16x8 af[4], bf[4];
#pragma unroll
        for (int im = 0; im < 4; ++im)
            af[im] = *(const bf16x8*)&sA[(wm + im * 16 + lr) * BK + quad * 8];
#pragma unroll
        for (int in = 0; in < 4; ++in)
            bf[in] = *(const bf16x8*)&sB[(wn + in * 16 + lr) * BK + quad * 8];

#pragma unroll
        for (int im = 0; im < 4; ++im)
#pragma unroll
            for (int in = 0; in < 4; ++in)
                acc[im][in] = __builtin_amdgcn_mfma_f32_16x16x32_bf16(
                    af[im], bf[in], acc[im][in], 0, 0, 0);
    }

    float bv[4];
#pragma unroll
    for (int in = 0; in < 4; ++in)
        bv[in] = bias[n0 + wn + in * 16 + lr];

#pragma unroll
    for (int im = 0; im < 4; ++im)
#pragma unroll
        for (int in = 0; in < 4; ++in) {
            const int gn = n0 + wn + in * 16 + lr;
#pragma unroll
            for (int r = 0; r < 4; ++r) {
                const int gm = m0 + wm + im * 16 + quad * 4 + r;
                C[(size_t)gm * NDIM + gn] = acc[im][in][r] + bv[in];
            }
        }
}

// ---------------------------------------------------------------------------
// Host: sign mask s(k,b) = sign(mult[k^b][b][k]); bit (k*8+b) set iff negative
// ---------------------------------------------------------------------------
static unsigned long long build_sign_mask() {
    static const int lines[7][3] = {{1,2,3},{1,4,5},{1,7,6},{2,4,6},{2,5,7},{3,4,7},{3,6,5}};
    float mult[8][8][8] = {};
    for (int i = 0; i < 8; ++i) { mult[0][i][i] = 1.f; mult[i][0][i] = 1.f; }
    for (int i = 1; i < 8; ++i) mult[i][i][0] = -1.f;
    for (int l = 0; l < 7; ++l) {
        const int i = lines[l][0], j = lines[l][1], k = lines[l][2];
        mult[i][j][k] = 1.f;  mult[j][k][i] = 1.f;  mult[k][i][j] = 1.f;
        mult[j][i][k] = -1.f; mult[k][j][i] = -1.f; mult[i][k][j] = -1.f;
    }
    unsigned long long m = 0;
    for (int k = 0; k < 8; ++k)
        for (int b = 0; b < 8; ++b)
            if (mult[k ^ b][b][k] < 0.f) m |= 1ull << (k * 8 + b);
    return m;
}

extern "C" void kernel_launch(void* const* d_in, const int* in_sizes, int n_in,
                              void* d_out, int out_size, void* d_ws, size_t ws_size,
                              hipStream_t stream) {
    const float* x    = (const float*)d_in[0];  // [8, 2048, 4096] fp32
    const float* w    = (const float*)d_in[1];  // [512, 512, 8]   fp32
    const float* bias = (const float*)d_in[2];  // [4096]          fp32
    float* out = (float*)d_out;                 // [8, 2048, 4096] fp32

    const int M = in_sizes[0] / KDIM;           // 16384
    const unsigned long long smask = build_sign_mask();

    const size_t WEFF_BYTES = (size_t)NDIM * KDIM * sizeof(ushort_t);  // 32 MiB
    const size_t XB_BYTES   = (size_t)M * KDIM * sizeof(ushort_t);     // 128 MiB

    if (ws_size >= WEFF_BYTES + XB_BYTES) {
        ushort_t* weff = (ushort_t*)d_ws;
        ushort_t* xb   = (ushort_t*)((char*)d_ws + WEFF_BYTES);
        convert_x<<<(int)((size_t)M * KDIM / (8 * 256)), 256, 0, stream>>>(x, xb);
        build_weff<<<NDIM * IN_OCT / 256, 256, 0, stream>>>(w, weff, smask);
        dim3 grid(NDIM / BN, M / BM);
        oct_gemm<<<grid, 256, 0, stream>>>(xb, weff, bias, out);
    } else {
        dim3 grid(NDIM / BN, M / BM);
        oct_gemm_fused<<<grid, 256, 0, stream>>>(x, w, bias, out, smask);
    }
}